// Round 7
// baseline (370.678 us; speedup 1.0000x reference)
//
#include <hip/hip_runtime.h>
#include <stdint.h>

// dims
#define BB 512
#define SS 64
#define HH 1024
#define EE 256
#define VV 128

typedef __attribute__((ext_vector_type(8))) short bf16x8;
typedef __attribute__((ext_vector_type(4))) float f32x4;
typedef __attribute__((ext_vector_type(8))) unsigned short u16x8;

// ---- workspace layout (bytes, all 256-aligned) ----
constexpr size_t OFF_SCRATCH = 0;                         // 64MB scratch (gate partial-1)
constexpr size_t OFF_OUTW  = OFF_SCRATCH + 67108864UL;    // 128x1024 bf16
constexpr size_t OFF_HID0  = OFF_OUTW  + 262144UL;        // 512x1024 bf16 (input hidden[0])
constexpr size_t OFF_HLAST = OFF_HID0  + 1048576UL;       // 512x1024 bf16 (input hidden[1]) — contiguous after HID0
constexpr size_t OFF_UT    = OFF_HLAST + 1048576UL;       // 1024x1024 bf16 (U^T)
constexpr size_t OFF_WT    = OFF_UT    + 2097152UL;       // 1024x1024 bf16 (W^T)
constexpr size_t OFF_T2    = OFF_WT    + 2097152UL;       // 512x1024 f32
constexpr size_t OFF_E     = OFF_T2    + 2097152UL;       // 512x64 f32
constexpr size_t OFF_EMB   = OFF_E     + 131072UL;        // 512x256 bf16
constexpr size_t OFF_CT    = OFF_EMB   + 262144UL;        // 512x1024 bf16
constexpr size_t OFF_G     = OFF_CT    + 1048576UL;       // 512x4096 f32 (gate partial-0)
constexpr size_t OFF_H0B   = OFF_G     + 8388608UL;       // 512x1024 bf16
constexpr size_t OFF_H1B   = OFF_H0B   + 1048576UL;       // 512x1024 bf16

__device__ __forceinline__ unsigned short f2bf(float f) {
  unsigned int u = __float_as_uint(f);
  unsigned int r = (u + 0x7FFFu + ((u >> 16) & 1u)) >> 16;
  return (unsigned short)r;
}
__device__ __forceinline__ float bf2f(unsigned short h) {
  return __uint_as_float(((unsigned int)h) << 16);
}

__device__ __forceinline__ void gload_lds16(const void* g, void* l) {
  __builtin_amdgcn_global_load_lds(
      (const __attribute__((address_space(1))) unsigned int*)g,
      (__attribute__((address_space(3))) unsigned int*)l, 16, 0, 0);
}

// ---------------- small conversions: hid (both layers, contiguous) + out_w ----------------
__global__ __launch_bounds__(256) void cvt_small(const float* __restrict__ hid,
                                                 const float* __restrict__ outw,
                                                 char* __restrict__ ws) {
  int i = blockIdx.x * 256 + threadIdx.x;  // 294912 float4 units
  const float4* src;
  ushort4* dst;
  int j;
  if (i < 262144) { src = (const float4*)hid;  dst = (ushort4*)(ws + OFF_HID0); j = i; }
  else            { src = (const float4*)outw; dst = (ushort4*)(ws + OFF_OUTW); j = i - 262144; }
  float4 v = src[j];
  ushort4 o;
  o.x = f2bf(v.x); o.y = f2bf(v.y); o.z = f2bf(v.z); o.w = f2bf(v.w);
  dst[j] = o;
}

// ---------------- transpose-convert U and W (z selects) ----------------
__global__ void transpose_cvt2(const float* __restrict__ U, const float* __restrict__ W,
                               char* __restrict__ ws) {
  __shared__ float tile[32][33];
  const float* in = blockIdx.z ? W : U;
  unsigned short* out = (unsigned short*)(ws + (blockIdx.z ? OFF_WT : OFF_UT));
  int bc = blockIdx.x * 32, br = blockIdx.y * 32;
  int tx = threadIdx.x & 31, ty = threadIdx.x >> 5;
#pragma unroll
  for (int i = 0; i < 32; i += 8)
    tile[ty + i][tx] = in[(long)(br + ty + i) * HH + bc + tx];
  __syncthreads();
#pragma unroll
  for (int i = 0; i < 32; i += 8)
    out[(long)(bc + ty + i) * HH + br + tx] = f2bf(tile[tx][ty + i]);
}

// ---------------- embedded token gather -> bf16 ----------------
__global__ void build_xemb(const int* __restrict__ ids, const float* __restrict__ emb,
                           unsigned short* __restrict__ embb) {
  int t = blockIdx.x * 256 + threadIdx.x;  // 32768 float4s
  int b = t >> 6, c4 = t & 63;
  float4 v = ((const float4*)(emb + (long)ids[b] * 256))[c4];
  ushort4 o;
  o.x = f2bf(v.x); o.y = f2bf(v.y); o.z = f2bf(v.z); o.w = f2bf(v.w);
  ((ushort4*)embb)[t] = o;
}

// ---------------- segmented bf16 GEMM, split-K; B either bf16 (gload_lds) or f32 (reg-cvt) ----
template <int BF32>
__global__ __launch_bounds__(256) void gemm_seg(
    const unsigned short* __restrict__ A0, int KA0,
    const unsigned short* __restrict__ A1, int KA1,
    const unsigned short* __restrict__ A2,
    const void* __restrict__ B0v, int KB0, const void* __restrict__ B1v,
    float* __restrict__ C0p, float* __restrict__ C1p, int N, int Ktot, int Khalf) {
  __shared__ alignas(128) unsigned short lA[128 * 64];
  __shared__ alignas(128) unsigned short lB[64 * 64];
  const int tid = threadIdx.x;
  const int lane = tid & 63, wid = tid >> 6;
  const int wr = wid >> 1, wc = wid & 1;
  const int fr = lane & 15, fg = lane >> 4;
  f32x4 acc[4][2] = {};
  const long rowA0 = (long)blockIdx.x * 128;
  const long rowB0 = (long)blockIdx.y * 64;
  const int ktb = blockIdx.z * Khalf;
  int kte = ktb + Khalf; if (kte > Ktot) kte = Ktot;
  float* C = blockIdx.z ? C1p : C0p;
  for (int kt = ktb; kt < kte; kt += 64) {
    const unsigned short* Ap; int ka, lda;
    if (kt < KA0)            { Ap = A0; ka = kt;             lda = KA0; }
    else if (kt < KA0 + KA1) { Ap = A1; ka = kt - KA0;       lda = KA1; }
    else                     { Ap = A2; ka = kt - KA0 - KA1; lda = 1024; }
    if constexpr (BF32) {
      // B: f32 -> reg -> cvt -> swizzled LDS
      const float* Bp; int kb, ldb;
      if (kt < KB0) { Bp = (const float*)B0v; kb = kt;       ldb = KB0; }
      else          { Bp = (const float*)B1v; kb = kt - KB0; ldb = 1024; }
      const int brow = tid >> 2, bkq = tid & 3;
      const f32x4* bs = (const f32x4*)(Bp + (rowB0 + brow) * (long)ldb + kb) + bkq * 4;
      f32x4 q0 = bs[0], q1 = bs[1], q2 = bs[2], q3 = bs[3];
#pragma unroll
      for (int j = 0; j < 4; ++j) {
        int c = j * 256 + tid;
        int r = c >> 3, cc = c & 7;
        int sc = cc ^ ((r >> 1) & 7);
        gload_lds16(Ap + (rowA0 + r) * (long)lda + ka + sc * 8, &lA[c * 8]);
      }
      const int bx = (brow >> 1) & 7;
      u16x8 w0, w1;
#pragma unroll
      for (int j = 0; j < 4; ++j) {
        w0[j] = f2bf(q0[j]); w0[4 + j] = f2bf(q1[j]);
        w1[j] = f2bf(q2[j]); w1[4 + j] = f2bf(q3[j]);
      }
      *(u16x8*)&lB[brow * 64 + (((bkq * 2) ^ bx) * 8)] = w0;
      *(u16x8*)&lB[brow * 64 + (((bkq * 2 + 1) ^ bx) * 8)] = w1;
    } else {
      const unsigned short* Bp; int kb, ldb;
      if (kt < KB0) { Bp = (const unsigned short*)B0v; kb = kt;       ldb = KB0; }
      else          { Bp = (const unsigned short*)B1v; kb = kt - KB0; ldb = 1024; }
#pragma unroll
      for (int j = 0; j < 4; ++j) {
        int c = j * 256 + tid;
        int r = c >> 3, cc = c & 7;
        int sc = cc ^ ((r >> 1) & 7);
        gload_lds16(Ap + (rowA0 + r) * (long)lda + ka + sc * 8, &lA[c * 8]);
      }
#pragma unroll
      for (int j = 0; j < 2; ++j) {
        int c = j * 256 + tid;
        int r = c >> 3, cc = c & 7;
        int sc = cc ^ ((r >> 1) & 7);
        gload_lds16(Bp + (rowB0 + r) * (long)ldb + kb + sc * 8, &lB[c * 8]);
      }
    }
    __syncthreads();
#pragma unroll
    for (int kk = 0; kk < 64; kk += 32) {
      bf16x8 af[4], bfv[2];
#pragma unroll
      for (int m = 0; m < 4; ++m) {
        int row = wr * 64 + m * 16 + fr;
        int ch = ((kk >> 3) + fg) ^ ((row >> 1) & 7);
        af[m] = *(const bf16x8*)&lA[row * 64 + ch * 8];
      }
#pragma unroll
      for (int n = 0; n < 2; ++n) {
        int row = wc * 32 + n * 16 + fr;
        int ch = ((kk >> 3) + fg) ^ ((row >> 1) & 7);
        bfv[n] = *(const bf16x8*)&lB[row * 64 + ch * 8];
      }
#pragma unroll
      for (int m = 0; m < 4; ++m)
#pragma unroll
        for (int n = 0; n < 2; ++n)
          acc[m][n] = __builtin_amdgcn_mfma_f32_16x16x32_bf16(af[m], bfv[n],
                                                              acc[m][n], 0, 0, 0);
    }
    __syncthreads();
  }
#pragma unroll
  for (int m = 0; m < 4; ++m)
#pragma unroll
    for (int n = 0; n < 2; ++n)
#pragma unroll
      for (int r = 0; r < 4; ++r) {
        long grow = rowA0 + wr * 64 + m * 16 + fg * 4 + r;
        long gcol = rowB0 + wc * 32 + n * 16 + fr;
        C[grow * N + gcol] = acc[m][n][r];
      }
}

// ---------------- out projection, split-K, atomic accumulate ----------------
__global__ __launch_bounds__(256) void gemm_outproj(
    const unsigned short* __restrict__ A, const unsigned short* __restrict__ Bt,
    float* __restrict__ C) {
  __shared__ alignas(128) unsigned short lA[128 * 64];
  __shared__ alignas(128) unsigned short lB[128 * 64];
  const int tid = threadIdx.x;
  const int lane = tid & 63, wid = tid >> 6;
  const int wr = wid >> 1, wc = wid & 1;
  const int fr = lane & 15, fg = lane >> 4;
  f32x4 acc[4][4] = {};
  const long rowA0 = (long)blockIdx.x * 128;
  const int k0 = blockIdx.y * 128;
  for (int kt = k0; kt < k0 + 128; kt += 64) {
#pragma unroll
    for (int j = 0; j < 4; ++j) {
      int c = j * 256 + tid;
      int r = c >> 3, cc = c & 7;
      gload_lds16(A + (rowA0 + r) * 1024 + kt + cc * 8, &lA[c * 8]);
    }
#pragma unroll
    for (int j = 0; j < 4; ++j) {
      int c = j * 256 + tid;
      int r = c >> 3, cc = c & 7;
      gload_lds16(Bt + (long)r * 1024 + kt + cc * 8, &lB[c * 8]);
    }
    __syncthreads();
#pragma unroll
    for (int kk = 0; kk < 64; kk += 32) {
      bf16x8 af[4], bfv[4];
#pragma unroll
      for (int m = 0; m < 4; ++m)
        af[m] = *(const bf16x8*)&lA[(wr * 64 + m * 16 + fr) * 64 + kk + fg * 8];
#pragma unroll
      for (int n = 0; n < 4; ++n)
        bfv[n] = *(const bf16x8*)&lB[(wc * 64 + n * 16 + fr) * 64 + kk + fg * 8];
#pragma unroll
      for (int m = 0; m < 4; ++m)
#pragma unroll
        for (int n = 0; n < 4; ++n)
          acc[m][n] = __builtin_amdgcn_mfma_f32_16x16x32_bf16(af[m], bfv[n],
                                                              acc[m][n], 0, 0, 0);
    }
    __syncthreads();
  }
#pragma unroll
  for (int m = 0; m < 4; ++m)
#pragma unroll
    for (int n = 0; n < 4; ++n)
#pragma unroll
      for (int r = 0; r < 4; ++r) {
        long grow = rowA0 + wr * 64 + m * 16 + fg * 4 + r;
        long gcol = wc * 64 + n * 16 + fr;
        atomicAdd(&C[grow * 128 + gcol], acc[m][n][r]);
      }
}

__global__ void init_out_bias(const float* __restrict__ ob, float* __restrict__ out) {
  int i = blockIdx.x * 256 + threadIdx.x;
  out[i] = ob[i & 127];
}

// ---------------- 256x256 score GEMM, A = enc f32 on-the-fly cvt, 1 barrier/K-tile ----------
// LDS per buf (32768 shorts): regions 0=A.kh0 1=A.kh1 2=B.kh0 3=B.kh1, each [256][32] bf16,
// slot-swizzled (phys slot = logical ^ ((row>>1)&3)). Counted vmcnt pipeline:
// entering iter u: outstanding = A(u+1) regs (8, oldest). Per iter: stageB(nxt,u+1)(4),
// [kh0 compute], writeA(nxt) (compiler waits areg: vmcnt(4)), issueA(u+2)(8),
// [kh1 compute], lgkm(0), vmcnt(8) (drain B(u+1)), raw barrier.
__global__ __launch_bounds__(512, 2) void gemm_score256(
    const float* __restrict__ Af, const unsigned short* __restrict__ Bt,
    const float* __restrict__ t2, const float* __restrict__ Vw,
    float* __restrict__ e) {
  extern __shared__ unsigned short smem[];  // 2 bufs x 32768 shorts = 128 KiB
  const int tid = threadIdx.x;
  const int lane = tid & 63, wid = tid >> 6;
  const int wr = wid >> 2;       // M half (128 rows)
  const int wcc = wid & 3;       // N quarter (64 cols)
  const int fr = lane & 15, fg = lane >> 4;
  int flat = blockIdx.y * 4 + blockIdx.x;
  int swz = (flat & 7) * 64 + (flat >> 3);     // XCD-chunked swizzle (512 = 8x64)
  const long rowA0 = (long)(swz >> 2) * 256;
  const long rowB0 = (long)(swz & 3) * 256;

  f32x4 acc[8][4] = {};

  // A staging: thread -> (arow = tid>>1, akh = tid&1), 32 floats of one row-khalf
  const int arow = tid >> 1, akh = tid & 1;
  const float* ag = Af + (rowA0 + arow) * 1024 + akh * 32;
  const int awx = (arow >> 1) & 3;
  f32x4 areg[8];

  auto issueA = [&](int kt) {
    const f32x4* p = (const f32x4*)(ag + kt * 64);
#pragma unroll
    for (int j = 0; j < 8; ++j) areg[j] = p[j];
  };
  auto writeA = [&](int buf) {
    unsigned short* wb = smem + buf * 32768 + akh * 8192 + arow * 32;
#pragma unroll
    for (int s = 0; s < 4; ++s) {
      u16x8 o;
#pragma unroll
      for (int q = 0; q < 8; ++q) o[q] = f2bf(areg[s * 2 + (q >> 2)][q & 3]);
      *(u16x8*)(wb + ((s ^ awx) * 8)) = o;
    }
  };
  auto stageB = [&](int buf, int kt) {
#pragma unroll
    for (int kh = 0; kh < 2; ++kh) {
      unsigned short* dst = smem + buf * 32768 + (2 + kh) * 8192;
      int kb = kt * 64 + kh * 32;
#pragma unroll
      for (int j = 0; j < 2; ++j) {
        int c = j * 512 + tid;
        int row = c >> 2;
        int fgl = (c & 3) ^ ((row >> 1) & 3);
        gload_lds16(Bt + (rowB0 + row) * 1024L + kb + fgl * 8, dst + c * 8);
      }
    }
  };
  auto readA4 = [&](int buf, int kh, int mh, bf16x8* af) {
    const unsigned short* rg = smem + buf * 32768 + kh * 8192;
#pragma unroll
    for (int m = 0; m < 4; ++m) {
      int row = wr * 128 + mh * 64 + m * 16 + fr;
      int slot = fg ^ ((row >> 1) & 3);
      af[m] = *(const bf16x8*)(rg + row * 32 + slot * 8);
    }
  };
  auto readB4 = [&](int buf, int kh, bf16x8* bv) {
    const unsigned short* rg = smem + buf * 32768 + (2 + kh) * 8192;
#pragma unroll
    for (int n = 0; n < 4; ++n) {
      int row = wcc * 64 + n * 16 + fr;
      int slot = fg ^ ((row >> 1) & 3);
      bv[n] = *(const bf16x8*)(rg + row * 32 + slot * 8);
    }
  };
  auto mfma16 = [&](int mh, const bf16x8* af, const bf16x8* bv) {
    __builtin_amdgcn_s_setprio(1);
#pragma unroll
    for (int m = 0; m < 4; ++m)
#pragma unroll
      for (int n = 0; n < 4; ++n)
        acc[mh * 4 + m][n] = __builtin_amdgcn_mfma_f32_16x16x32_bf16(
            af[m], bv[n], acc[mh * 4 + m][n], 0, 0, 0);
    __builtin_amdgcn_s_setprio(0);
  };

  // ---- prologue: tile0 -> buf0; A(1) in flight ----
  issueA(0);
  stageB(0, 0);
  asm volatile("s_waitcnt vmcnt(4)" ::: "memory");   // A(0) regs done (4 newer gload_lds)
  writeA(0);
  issueA(1);
  asm volatile("s_waitcnt lgkmcnt(0)" ::: "memory"); // A-writes drained
  asm volatile("s_waitcnt vmcnt(8)" ::: "memory");   // B(0) gloads done; A(1) 8 outstanding
  __builtin_amdgcn_s_barrier();

#pragma unroll 2
  for (int u = 0; u < 16; ++u) {
    const int cur = u & 1, nxt = cur ^ 1;
    stageB(nxt, (u + 1) & 15);                       // B(u+1) -> buf[nxt] (region free)
    bf16x8 af[4], bv[4];
    readB4(cur, 0, bv);
    readA4(cur, 0, 0, af);
    mfma16(0, af, bv);
    readA4(cur, 0, 1, af);
    mfma16(1, af, bv);
    writeA(nxt);                                     // A(u+1) -> buf[nxt] (auto vmcnt)
    issueA((u + 2) & 15);                            // reg set freed by writeA
    readB4(cur, 1, bv);
    readA4(cur, 1, 0, af);
    mfma16(0, af, bv);
    readA4(cur, 1, 1, af);
    asm volatile("s_waitcnt lgkmcnt(0)" ::: "memory");  // drain ds_writes (+reads)
    mfma16(1, af, bv);
    asm volatile("s_waitcnt vmcnt(8)" ::: "memory");    // drain B(u+1); A(u+2) stays out
    __builtin_amdgcn_s_barrier();
  }
  asm volatile("s_waitcnt vmcnt(0)" ::: "memory");

  // ---- epilogue: e[row] += sum_cols tanh(acc + t2) * Vw ----
  float t2v[2][4], vw[4];
#pragma unroll
  for (int n = 0; n < 4; ++n) {
    long col = rowB0 + wcc * 64 + n * 16 + fr;
    vw[n] = Vw[col];
#pragma unroll
    for (int h = 0; h < 2; ++h) {
      long b = (rowA0 >> 6) + wr * 2 + h;
      t2v[h][n] = t2[b * HH + col];
    }
  }
#pragma unroll
  for (int i = 0; i < 8; ++i) {
    int hsel = i >> 2;
    float part[4] = {0.f, 0.f, 0.f, 0.f};
#pragma unroll
    for (int n = 0; n < 4; ++n) {
#pragma unroll
      for (int r = 0; r < 4; ++r) {
        float tval = acc[i][n][r] + t2v[hsel][n];
        float th = 1.f - 2.f / (__expf(2.f * tval) + 1.f);
        part[r] += th * vw[n];
      }
    }
#pragma unroll
    for (int r = 0; r < 4; ++r) {
      float p = part[r];
      p += __shfl_xor(p, 1);
      p += __shfl_xor(p, 2);
      p += __shfl_xor(p, 4);
      p += __shfl_xor(p, 8);
      if (fr == 0)
        atomicAdd(&e[rowA0 + wr * 128 + i * 16 + fg * 4 + r], p);
    }
  }
}

// ---------------- fused softmax (S=64) + context (reads enc f32, L3-warm) -> bf16 ----------
__global__ void softmax_ctx(const float* __restrict__ e,
                            const float* __restrict__ enc,
                            unsigned short* __restrict__ ctb) {
  __shared__ float als[2][64];
  const int tid = threadIdx.x;
  const int bpair = blockIdx.x;
  if (tid < 128) {
    int b = bpair * 2 + (tid >> 6), s = tid & 63;
    float v = e[b * 64 + s];
    float mx = v;
#pragma unroll
    for (int o = 32; o; o >>= 1) mx = fmaxf(mx, __shfl_xor(mx, o));
    float ex = __expf(v - mx);
    float sm = ex;
#pragma unroll
    for (int o = 32; o; o >>= 1) sm += __shfl_xor(sm, o);
    als[tid >> 6][s] = ex / sm;
  }
  __syncthreads();
  int bi = tid >> 7, hg = tid & 127;
  int b = bpair * 2 + bi;
  const float* er = enc + (long)b * (SS * HH) + hg * 8;
  float s[8] = {0.f, 0.f, 0.f, 0.f, 0.f, 0.f, 0.f, 0.f};
  for (int i = 0; i < 64; ++i) {
    float av = als[bi][i];
    f32x4 v0 = *(const f32x4*)(er + (long)i * HH);
    f32x4 v1 = *(const f32x4*)(er + (long)i * HH + 4);
#pragma unroll
    for (int j = 0; j < 4; ++j) { s[j] += av * v0[j]; s[4 + j] += av * v1[j]; }
  }
  unsigned short* dst = ctb + (long)b * HH + hg * 8;
#pragma unroll
  for (int j = 0; j < 8; ++j) dst[j] = f2bf(s[j]);
}

// ---------------- LSTM cell elementwise (sums two split-K partials) ----------------
__global__ void lstm_cell(const float* __restrict__ g0, const float* __restrict__ g1,
                          const float* __restrict__ bih, const float* __restrict__ bhh,
                          const float* __restrict__ cin,
                          float* __restrict__ hout, float* __restrict__ cout,
                          unsigned short* __restrict__ hb) {
  int idx = blockIdx.x * 256 + threadIdx.x;  // 512*1024
  int b = idx >> 10, h = idx & 1023;
  const float* gr0 = g0 + (long)b * 4096;
  const float* gr1 = g1 + (long)b * 4096;
  float gi = gr0[h] + gr1[h] + bih[h] + bhh[h];
  float gf = gr0[1024 + h] + gr1[1024 + h] + bih[1024 + h] + bhh[1024 + h];
  float gg = gr0[2048 + h] + gr1[2048 + h] + bih[2048 + h] + bhh[2048 + h];
  float go = gr0[3072 + h] + gr1[3072 + h] + bih[3072 + h] + bhh[3072 + h];
  float si = 1.f / (1.f + __expf(-gi));
  float sf = 1.f / (1.f + __expf(-gf));
  float so = 1.f / (1.f + __expf(-go));
  float tg = 1.f - 2.f / (__expf(2.f * gg) + 1.f);
  float c2 = sf * cin[idx] + si * tg;
  float tc = 1.f - 2.f / (__expf(2.f * c2) + 1.f);
  float h2 = so * tc;
  cout[idx] = c2;
  hout[idx] = h2;
  hb[idx] = f2bf(h2);
}

extern "C" void kernel_launch(void* const* d_in, const int* in_sizes, int n_in,
                              void* d_out, int out_size, void* d_ws, size_t ws_size,
                              hipStream_t stream) {
  const int* ids = (const int*)d_in[0];
  const float* hidden = (const float*)d_in[1];
  const float* cell = (const float*)d_in[2];
  const float* enc = (const float*)d_in[3];
  const float* emb = (const float*)d_in[4];
  const float* U = (const float*)d_in[5];
  const float* W = (const float*)d_in[6];
  const float* Vw = (const float*)d_in[7];
  const float* Wih0 = (const float*)d_in[8];
  const float* Whh0 = (const float*)d_in[9];
  const float* bih0 = (const float*)d_in[10];
  const float* bhh0 = (const float*)d_in[11];
  const float* Wih1 = (const float*)d_in[12];
  const float* Whh1 = (const float*)d_in[13];
  const float* bih1 = (const float*)d_in[14];
  const float* bhh1 = (const float*)d_in[15];
  const float* out_w = (const float*)d_in[16];
  const float* out_b = (const float*)d_in[17];
  float* out = (float*)d_out;
  char* ws = (char*)d_ws;
  (void)in_sizes; (void)n_in; (void)out_size; (void)ws_size;

  unsigned short* outwb  = (unsigned short*)(ws + OFF_OUTW);
  unsigned short* hid0b  = (unsigned short*)(ws + OFF_HID0);
  unsigned short* hlastb = (unsigned short*)(ws + OFF_HLAST);
  unsigned short* Utb    = (unsigned short*)(ws + OFF_UT);
  unsigned short* Wtb    = (unsigned short*)(ws + OFF_WT);
  float*          t2     = (float*)(ws + OFF_T2);
  float*          e      = (float*)(ws + OFF_E);
  unsigned short* embb   = (unsigned short*)(ws + OFF_EMB);
  unsigned short* ctb    = (unsigned short*)(ws + OFF_CT);
  float*          g      = (float*)(ws + OFF_G);
  float*          gB     = (float*)(ws + OFF_SCRATCH);
  unsigned short* h0b    = (unsigned short*)(ws + OFF_H0B);
  unsigned short* h1b    = (unsigned short*)(ws + OFF_H1B);

  float* out_logits = out;
  float* h_new = out + BB * VV;
  float* c_new = h_new + 2 * BB * HH;

  // ---- prep ----
  cvt_small<<<1152, 256, 0, stream>>>(hidden, out_w, ws);
  transpose_cvt2<<<dim3(32, 32, 2), 256, 0, stream>>>(U, W, ws);
  build_xemb<<<128, 256, 0, stream>>>(ids, emb, embb);
  hipMemsetAsync(e, 0, (size_t)BB * SS * 4, stream);

  // ---- t2 = hidden[1] @ W (B = Wt bf16) ----
  gemm_seg<0><<<dim3(4, 16, 1), 256, 0, stream>>>(hlastb, 1024, nullptr, 0, nullptr,
                                                  Wtb, 1024, nullptr, t2, t2, HH, 1024, 1024);

  // ---- scores e (A = enc f32 on-the-fly) ----
  (void)hipFuncSetAttribute(reinterpret_cast<const void*>(gemm_score256),
                            hipFuncAttributeMaxDynamicSharedMemorySize, 131072);
  gemm_score256<<<dim3(4, 128), 512, 131072, stream>>>(enc, Utb, t2, Vw, e);

  // ---- fused softmax + context (enc f32, L3-warm) ----
  softmax_ctx<<<256, 256, 0, stream>>>(e, enc, ctb);

  // ---- LSTM layer 0: g = [emb | ct | hid0] @ [Wih0 | Whh0]^T (weights f32) ----
  gemm_seg<1><<<dim3(4, 64, 2), 256, 0, stream>>>(embb, 256, ctb, 1024, hid0b,
                                                  Wih0, 1280, Whh0, g, gB, 4 * HH, 2304, 1152);
  lstm_cell<<<BB * HH / 256, 256, 0, stream>>>(g, gB, bih0, bhh0, cell, h_new, c_new, h0b);

  // ---- LSTM layer 1: g = [h0 | hid1] @ [Wih1 | Whh1]^T (weights f32) ----
  gemm_seg<1><<<dim3(4, 64, 2), 256, 0, stream>>>(h0b, 1024, hlastb, 1024, nullptr,
                                                  Wih1, 1024, Whh1, g, gB, 4 * HH, 2048, 1024);
  lstm_cell<<<BB * HH / 256, 256, 0, stream>>>(g, gB, bih1, bhh1, cell + BB * HH,
                                               h_new + BB * HH, c_new + BB * HH, h1b);

  // ---- output projection ----
  init_out_bias<<<BB * VV / 256, 256, 0, stream>>>(out_b, out_logits);
  gemm_outproj<<<dim3(4, 8), 256, 0, stream>>>(h1b, outwb, out_logits);
}

// Round 8
// 260.566 us; speedup vs baseline: 1.4226x; 1.4226x over previous
//
#include <hip/hip_runtime.h>
#include <stdint.h>

// dims
#define BB 512
#define SS 64
#define HH 1024
#define EE 256
#define VV 128

typedef __attribute__((ext_vector_type(8))) short bf16x8;
typedef __attribute__((ext_vector_type(4))) float f32x4;
typedef __attribute__((ext_vector_type(8))) unsigned short u16x8;

// ---- workspace layout (bytes, all 256-aligned) ----
constexpr size_t OFF_SCRATCH = 0;                         // 64MB scratch (gate partial-1)
constexpr size_t OFF_OUTW  = OFF_SCRATCH + 67108864UL;    // 128x1024 bf16
constexpr size_t OFF_HID0  = OFF_OUTW  + 262144UL;        // 512x1024 bf16 (input hidden[0])
constexpr size_t OFF_HLAST = OFF_HID0  + 1048576UL;       // 512x1024 bf16 (input hidden[1])
constexpr size_t OFF_UT    = OFF_HLAST + 1048576UL;       // 1024x1024 bf16 (U^T)
constexpr size_t OFF_WT    = OFF_UT    + 2097152UL;       // 1024x1024 bf16 (W^T)
constexpr size_t OFF_T2    = OFF_WT    + 2097152UL;       // 512x1024 f32
constexpr size_t OFF_E     = OFF_T2    + 2097152UL;       // 512x64 f32
constexpr size_t OFF_EMB   = OFF_E     + 131072UL;        // 512x256 bf16
constexpr size_t OFF_CT    = OFF_EMB   + 262144UL;        // 512x1024 bf16
constexpr size_t OFF_G     = OFF_CT    + 1048576UL;       // 512x4096 f32 (gate partial-0)
constexpr size_t OFF_H0B   = OFF_G     + 8388608UL;       // 512x1024 bf16
constexpr size_t OFF_H1B   = OFF_H0B   + 1048576UL;       // 512x1024 bf16

__device__ __forceinline__ unsigned short f2bf(float f) {
  unsigned int u = __float_as_uint(f);
  unsigned int r = (u + 0x7FFFu + ((u >> 16) & 1u)) >> 16;
  return (unsigned short)r;
}
__device__ __forceinline__ float bf2f(unsigned short h) {
  return __uint_as_float(((unsigned int)h) << 16);
}

__device__ __forceinline__ void gload_lds16(const void* g, void* l) {
  __builtin_amdgcn_global_load_lds(
      (const __attribute__((address_space(1))) unsigned int*)g,
      (__attribute__((address_space(3))) unsigned int*)l, 16, 0, 0);
}

// ---------------- small conversions: hid (both layers, contiguous) + out_w ----------------
__global__ __launch_bounds__(256) void cvt_small(const float* __restrict__ hid,
                                                 const float* __restrict__ outw,
                                                 char* __restrict__ ws) {
  int i = blockIdx.x * 256 + threadIdx.x;  // 294912 float4 units
  const float4* src;
  ushort4* dst;
  int j;
  if (i < 262144) { src = (const float4*)hid;  dst = (ushort4*)(ws + OFF_HID0); j = i; }
  else            { src = (const float4*)outw; dst = (ushort4*)(ws + OFF_OUTW); j = i - 262144; }
  float4 v = src[j];
  ushort4 o;
  o.x = f2bf(v.x); o.y = f2bf(v.y); o.z = f2bf(v.z); o.w = f2bf(v.w);
  dst[j] = o;
}

// ---------------- transpose-convert U and W (z selects) ----------------
__global__ void transpose_cvt2(const float* __restrict__ U, const float* __restrict__ W,
                               char* __restrict__ ws) {
  __shared__ float tile[32][33];
  const float* in = blockIdx.z ? W : U;
  unsigned short* out = (unsigned short*)(ws + (blockIdx.z ? OFF_WT : OFF_UT));
  int bc = blockIdx.x * 32, br = blockIdx.y * 32;
  int tx = threadIdx.x & 31, ty = threadIdx.x >> 5;
#pragma unroll
  for (int i = 0; i < 32; i += 8)
    tile[ty + i][tx] = in[(long)(br + ty + i) * HH + bc + tx];
  __syncthreads();
#pragma unroll
  for (int i = 0; i < 32; i += 8)
    out[(long)(bc + ty + i) * HH + br + tx] = f2bf(tile[tx][ty + i]);
}

// ---------------- embedded token gather -> bf16 ----------------
__global__ void build_xemb(const int* __restrict__ ids, const float* __restrict__ emb,
                           unsigned short* __restrict__ embb) {
  int t = blockIdx.x * 256 + threadIdx.x;  // 32768 float4s
  int b = t >> 6, c4 = t & 63;
  float4 v = ((const float4*)(emb + (long)ids[b] * 256))[c4];
  ushort4 o;
  o.x = f2bf(v.x); o.y = f2bf(v.y); o.z = f2bf(v.z); o.w = f2bf(v.w);
  ((ushort4*)embb)[t] = o;
}

// ---------------- segmented bf16 GEMM, split-K; B either bf16 (gload_lds) or f32 (reg-cvt) ----
template <int BF32>
__global__ __launch_bounds__(256) void gemm_seg(
    const unsigned short* __restrict__ A0, int KA0,
    const unsigned short* __restrict__ A1, int KA1,
    const unsigned short* __restrict__ A2,
    const void* __restrict__ B0v, int KB0, const void* __restrict__ B1v,
    float* __restrict__ C0p, float* __restrict__ C1p, int N, int Ktot, int Khalf) {
  __shared__ alignas(128) unsigned short lA[128 * 64];
  __shared__ alignas(128) unsigned short lB[64 * 64];
  const int tid = threadIdx.x;
  const int lane = tid & 63, wid = tid >> 6;
  const int wr = wid >> 1, wc = wid & 1;
  const int fr = lane & 15, fg = lane >> 4;
  f32x4 acc[4][2] = {};
  const long rowA0 = (long)blockIdx.x * 128;
  const long rowB0 = (long)blockIdx.y * 64;
  const int ktb = blockIdx.z * Khalf;
  int kte = ktb + Khalf; if (kte > Ktot) kte = Ktot;
  float* C = blockIdx.z ? C1p : C0p;
  for (int kt = ktb; kt < kte; kt += 64) {
    const unsigned short* Ap; int ka, lda;
    if (kt < KA0)            { Ap = A0; ka = kt;             lda = KA0; }
    else if (kt < KA0 + KA1) { Ap = A1; ka = kt - KA0;       lda = KA1; }
    else                     { Ap = A2; ka = kt - KA0 - KA1; lda = 1024; }
    if constexpr (BF32) {
      const float* Bp; int kb, ldb;
      if (kt < KB0) { Bp = (const float*)B0v; kb = kt;       ldb = KB0; }
      else          { Bp = (const float*)B1v; kb = kt - KB0; ldb = 1024; }
      const int brow = tid >> 2, bkq = tid & 3;
      const f32x4* bs = (const f32x4*)(Bp + (rowB0 + brow) * (long)ldb + kb) + bkq * 4;
      f32x4 q0 = bs[0], q1 = bs[1], q2 = bs[2], q3 = bs[3];
#pragma unroll
      for (int j = 0; j < 4; ++j) {
        int c = j * 256 + tid;
        int r = c >> 3, cc = c & 7;
        int sc = cc ^ ((r >> 1) & 7);
        gload_lds16(Ap + (rowA0 + r) * (long)lda + ka + sc * 8, &lA[c * 8]);
      }
      const int bx = (brow >> 1) & 7;
      u16x8 w0, w1;
#pragma unroll
      for (int j = 0; j < 4; ++j) {
        w0[j] = f2bf(q0[j]); w0[4 + j] = f2bf(q1[j]);
        w1[j] = f2bf(q2[j]); w1[4 + j] = f2bf(q3[j]);
      }
      *(u16x8*)&lB[brow * 64 + (((bkq * 2) ^ bx) * 8)] = w0;
      *(u16x8*)&lB[brow * 64 + (((bkq * 2 + 1) ^ bx) * 8)] = w1;
    } else {
      const unsigned short* Bp; int kb, ldb;
      if (kt < KB0) { Bp = (const unsigned short*)B0v; kb = kt;       ldb = KB0; }
      else          { Bp = (const unsigned short*)B1v; kb = kt - KB0; ldb = 1024; }
#pragma unroll
      for (int j = 0; j < 4; ++j) {
        int c = j * 256 + tid;
        int r = c >> 3, cc = c & 7;
        int sc = cc ^ ((r >> 1) & 7);
        gload_lds16(Ap + (rowA0 + r) * (long)lda + ka + sc * 8, &lA[c * 8]);
      }
#pragma unroll
      for (int j = 0; j < 2; ++j) {
        int c = j * 256 + tid;
        int r = c >> 3, cc = c & 7;
        int sc = cc ^ ((r >> 1) & 7);
        gload_lds16(Bp + (rowB0 + r) * (long)ldb + kb + sc * 8, &lB[c * 8]);
      }
    }
    __syncthreads();
#pragma unroll
    for (int kk = 0; kk < 64; kk += 32) {
      bf16x8 af[4], bfv[2];
#pragma unroll
      for (int m = 0; m < 4; ++m) {
        int row = wr * 64 + m * 16 + fr;
        int ch = ((kk >> 3) + fg) ^ ((row >> 1) & 7);
        af[m] = *(const bf16x8*)&lA[row * 64 + ch * 8];
      }
#pragma unroll
      for (int n = 0; n < 2; ++n) {
        int row = wc * 32 + n * 16 + fr;
        int ch = ((kk >> 3) + fg) ^ ((row >> 1) & 7);
        bfv[n] = *(const bf16x8*)&lB[row * 64 + ch * 8];
      }
#pragma unroll
      for (int m = 0; m < 4; ++m)
#pragma unroll
        for (int n = 0; n < 2; ++n)
          acc[m][n] = __builtin_amdgcn_mfma_f32_16x16x32_bf16(af[m], bfv[n],
                                                              acc[m][n], 0, 0, 0);
    }
    __syncthreads();
  }
#pragma unroll
  for (int m = 0; m < 4; ++m)
#pragma unroll
    for (int n = 0; n < 2; ++n)
#pragma unroll
      for (int r = 0; r < 4; ++r) {
        long grow = rowA0 + wr * 64 + m * 16 + fg * 4 + r;
        long gcol = rowB0 + wc * 32 + n * 16 + fr;
        C[grow * N + gcol] = acc[m][n][r];
      }
}

// ---------------- out projection, split-K, atomic accumulate ----------------
__global__ __launch_bounds__(256) void gemm_outproj(
    const unsigned short* __restrict__ A, const unsigned short* __restrict__ Bt,
    float* __restrict__ C) {
  __shared__ alignas(128) unsigned short lA[128 * 64];
  __shared__ alignas(128) unsigned short lB[128 * 64];
  const int tid = threadIdx.x;
  const int lane = tid & 63, wid = tid >> 6;
  const int wr = wid >> 1, wc = wid & 1;
  const int fr = lane & 15, fg = lane >> 4;
  f32x4 acc[4][4] = {};
  const long rowA0 = (long)blockIdx.x * 128;
  const int k0 = blockIdx.y * 128;
  for (int kt = k0; kt < k0 + 128; kt += 64) {
#pragma unroll
    for (int j = 0; j < 4; ++j) {
      int c = j * 256 + tid;
      int r = c >> 3, cc = c & 7;
      gload_lds16(A + (rowA0 + r) * 1024 + kt + cc * 8, &lA[c * 8]);
    }
#pragma unroll
    for (int j = 0; j < 4; ++j) {
      int c = j * 256 + tid;
      int r = c >> 3, cc = c & 7;
      gload_lds16(Bt + (long)r * 1024 + kt + cc * 8, &lB[c * 8]);
    }
    __syncthreads();
#pragma unroll
    for (int kk = 0; kk < 64; kk += 32) {
      bf16x8 af[4], bfv[4];
#pragma unroll
      for (int m = 0; m < 4; ++m)
        af[m] = *(const bf16x8*)&lA[(wr * 64 + m * 16 + fr) * 64 + kk + fg * 8];
#pragma unroll
      for (int n = 0; n < 4; ++n)
        bfv[n] = *(const bf16x8*)&lB[(wc * 64 + n * 16 + fr) * 64 + kk + fg * 8];
#pragma unroll
      for (int m = 0; m < 4; ++m)
#pragma unroll
        for (int n = 0; n < 4; ++n)
          acc[m][n] = __builtin_amdgcn_mfma_f32_16x16x32_bf16(af[m], bfv[n],
                                                              acc[m][n], 0, 0, 0);
    }
    __syncthreads();
  }
#pragma unroll
  for (int m = 0; m < 4; ++m)
#pragma unroll
    for (int n = 0; n < 4; ++n)
#pragma unroll
      for (int r = 0; r < 4; ++r) {
        long grow = rowA0 + wr * 64 + m * 16 + fg * 4 + r;
        long gcol = wc * 64 + n * 16 + fr;
        atomicAdd(&C[grow * 128 + gcol], acc[m][n][r]);
      }
}

__global__ void init_out_bias(const float* __restrict__ ob, float* __restrict__ out) {
  int i = blockIdx.x * 256 + threadIdx.x;
  out[i] = ob[i & 127];
}

// ---------------- 128x256 fused score GEMM, A = enc f32 on-the-fly, 1 barrier/K-tile ------
// 512 thr (8 waves: 2 M-half x 4 N-quarter). acc 4x4x4 = 64 VGPR; areg 16 VGPR (no spill).
// LDS/buf (24576 shorts = 48KB): A[2kh][128][32] @0, B[2kh][256][32] @8192. Slot swizzle
// phys = logical ^ ((row>>1)&3). vmcnt invariant: entering iter u, A(u+1) 4 loads out.
__global__ __launch_bounds__(512, 2) void gemm_score128(
    const float* __restrict__ Af, const unsigned short* __restrict__ Bt,
    const float* __restrict__ t2, const float* __restrict__ Vw,
    float* __restrict__ e) {
  extern __shared__ unsigned short smem[];  // 2 x 24576 shorts = 96 KiB
  const int tid = threadIdx.x;
  const int lane = tid & 63, wid = tid >> 6;
  const int wr = wid >> 2;       // M half (64 rows)
  const int wcc = wid & 3;       // N quarter (64 cols)
  const int fr = lane & 15, fg = lane >> 4;
  // XCD swizzle: 1024 blocks = 8 chunks x 128; consecutive remap per XCD keeps
  // the 4 N-blocks of one A-panel adjacent -> A fetched once, B L2-resident.
  int flat = blockIdx.y * 4 + blockIdx.x;
  int swz = (flat & 7) * 128 + (flat >> 3);
  const long rowA0 = (long)(swz >> 2) * 128;   // M block (0..255)
  const long rowB0 = (long)(swz & 3) * 256;    // N block (0..3)

  f32x4 acc[4][4] = {};

  // A staging: thread -> (arow = tid>>2, akq = tid&3): 16 floats (row, cols akq*16..+15)
  const int arow = tid >> 2, akq = tid & 3;
  const int akh = akq >> 1, ach = akq & 1;     // k-half, col-half within kh
  const float* ag = Af + (rowA0 + arow) * 1024 + akq * 16;
  const int awx = (arow >> 1) & 3;
  f32x4 areg[4];

  auto issueA = [&](int kt) {
    const f32x4* p = (const f32x4*)(ag + kt * 64);
#pragma unroll
    for (int j = 0; j < 4; ++j) areg[j] = p[j];
  };
  auto writeA = [&](int buf) {
    unsigned short* wb = smem + buf * 24576 + akh * 4096 + arow * 32;
#pragma unroll
    for (int w = 0; w < 2; ++w) {
      u16x8 o;
#pragma unroll
      for (int q = 0; q < 8; ++q) o[q] = f2bf(areg[w * 2 + (q >> 2)][q & 3]);
      *(u16x8*)(wb + (((ach * 2 + w) ^ awx) * 8)) = o;
    }
  };
  auto stageB = [&](int buf, int kt) {
#pragma unroll
    for (int kh = 0; kh < 2; ++kh) {
      unsigned short* dst = smem + buf * 24576 + 8192 + kh * 8192;
      int kb = kt * 64 + kh * 32;
#pragma unroll
      for (int j = 0; j < 2; ++j) {
        int c = j * 512 + tid;
        int row = c >> 2;
        int fgl = (c & 3) ^ ((row >> 1) & 3);
        gload_lds16(Bt + (rowB0 + row) * 1024L + kb + fgl * 8, dst + c * 8);
      }
    }
  };
  auto readA4 = [&](int buf, int kh, bf16x8* af) {
    const unsigned short* rg = smem + buf * 24576 + kh * 4096;
#pragma unroll
    for (int m = 0; m < 4; ++m) {
      int row = wr * 64 + m * 16 + fr;
      int slot = fg ^ ((row >> 1) & 3);
      af[m] = *(const bf16x8*)(rg + row * 32 + slot * 8);
    }
  };
  auto readB4 = [&](int buf, int kh, bf16x8* bv) {
    const unsigned short* rg = smem + buf * 24576 + 8192 + kh * 8192;
#pragma unroll
    for (int n = 0; n < 4; ++n) {
      int row = wcc * 64 + n * 16 + fr;
      int slot = fg ^ ((row >> 1) & 3);
      bv[n] = *(const bf16x8*)(rg + row * 32 + slot * 8);
    }
  };
  auto mfma16 = [&](const bf16x8* af, const bf16x8* bv) {
    __builtin_amdgcn_s_setprio(1);
#pragma unroll
    for (int m = 0; m < 4; ++m)
#pragma unroll
      for (int n = 0; n < 4; ++n)
        acc[m][n] = __builtin_amdgcn_mfma_f32_16x16x32_bf16(af[m], bv[n],
                                                            acc[m][n], 0, 0, 0);
    __builtin_amdgcn_s_setprio(0);
  };

  // ---- prologue ----
  issueA(0);
  stageB(0, 0);
  asm volatile("s_waitcnt vmcnt(4)" ::: "memory");   // A(0) regs ready (B(0) 4 still out)
  writeA(0);
  issueA(1);
  asm volatile("s_waitcnt lgkmcnt(0)" ::: "memory");
  asm volatile("s_waitcnt vmcnt(4)" ::: "memory");   // B(0) done; A(1) 4 out
  __builtin_amdgcn_s_barrier();
  __builtin_amdgcn_sched_barrier(0);

#pragma unroll 2
  for (int u = 0; u < 16; ++u) {
    const int cur = u & 1, nxt = cur ^ 1;
    stageB(nxt, (u + 1) & 15);                       // +4 gloads
    bf16x8 af[4], bv[4];
    readB4(cur, 0, bv);
    readA4(cur, 0, af);
    mfma16(af, bv);
    writeA(nxt);                                     // data-dep drains A(u+1) loads
    issueA((u + 2) & 15);                            // +4 (B(u+1) oldest 4, A(u+2) 4)
    readB4(cur, 1, bv);
    readA4(cur, 1, af);
    asm volatile("s_waitcnt lgkmcnt(0)" ::: "memory");
    __builtin_amdgcn_sched_barrier(0);
    mfma16(af, bv);
    asm volatile("s_waitcnt vmcnt(4)" ::: "memory"); // B(u+1) done; A(u+2) stays out
    __builtin_amdgcn_s_barrier();
    __builtin_amdgcn_sched_barrier(0);
  }
  asm volatile("s_waitcnt vmcnt(0)" ::: "memory");

  // ---- epilogue: e[row] += sum_cols tanh(acc + t2) * Vw ----
  const long bidx = (rowA0 >> 6) + wr;               // one batch per wave M-half
  float t2v[4], vw[4];
#pragma unroll
  for (int n = 0; n < 4; ++n) {
    long col = rowB0 + wcc * 64 + n * 16 + fr;
    vw[n] = Vw[col];
    t2v[n] = t2[bidx * HH + col];
  }
#pragma unroll
  for (int i = 0; i < 4; ++i) {
    float part[4] = {0.f, 0.f, 0.f, 0.f};
#pragma unroll
    for (int n = 0; n < 4; ++n) {
#pragma unroll
      for (int r = 0; r < 4; ++r) {
        float tval = acc[i][n][r] + t2v[n];
        float th = 1.f - 2.f / (__expf(2.f * tval) + 1.f);
        part[r] += th * vw[n];
      }
    }
#pragma unroll
    for (int r = 0; r < 4; ++r) {
      float p = part[r];
      p += __shfl_xor(p, 1);
      p += __shfl_xor(p, 2);
      p += __shfl_xor(p, 4);
      p += __shfl_xor(p, 8);
      if (fr == 0)
        atomicAdd(&e[rowA0 + wr * 64 + i * 16 + fg * 4 + r], p);
    }
  }
}

// ---------------- fused softmax (S=64) + context (reads enc f32, L3-warm) -> bf16 ----------
__global__ void softmax_ctx(const float* __restrict__ e,
                            const float* __restrict__ enc,
                            unsigned short* __restrict__ ctb) {
  __shared__ float als[2][64];
  const int tid = threadIdx.x;
  const int bpair = blockIdx.x;
  if (tid < 128) {
    int b = bpair * 2 + (tid >> 6), s = tid & 63;
    float v = e[b * 64 + s];
    float mx = v;
#pragma unroll
    for (int o = 32; o; o >>= 1) mx = fmaxf(mx, __shfl_xor(mx, o));
    float ex = __expf(v - mx);
    float sm = ex;
#pragma unroll
    for (int o = 32; o; o >>= 1) sm += __shfl_xor(sm, o);
    als[tid >> 6][s] = ex / sm;
  }
  __syncthreads();
  int bi = tid >> 7, hg = tid & 127;
  int b = bpair * 2 + bi;
  const float* er = enc + (long)b * (SS * HH) + hg * 8;
  float s[8] = {0.f, 0.f, 0.f, 0.f, 0.f, 0.f, 0.f, 0.f};
  for (int i = 0; i < 64; ++i) {
    float av = als[bi][i];
    f32x4 v0 = *(const f32x4*)(er + (long)i * HH);
    f32x4 v1 = *(const f32x4*)(er + (long)i * HH + 4);
#pragma unroll
    for (int j = 0; j < 4; ++j) { s[j] += av * v0[j]; s[4 + j] += av * v1[j]; }
  }
  unsigned short* dst = ctb + (long)b * HH + hg * 8;
#pragma unroll
  for (int j = 0; j < 8; ++j) dst[j] = f2bf(s[j]);
}

// ---------------- LSTM cell elementwise (sums two split-K partials) ----------------
__global__ void lstm_cell(const float* __restrict__ g0, const float* __restrict__ g1,
                          const float* __restrict__ bih, const float* __restrict__ bhh,
                          const float* __restrict__ cin,
                          float* __restrict__ hout, float* __restrict__ cout,
                          unsigned short* __restrict__ hb) {
  int idx = blockIdx.x * 256 + threadIdx.x;  // 512*1024
  int b = idx >> 10, h = idx & 1023;
  const float* gr0 = g0 + (long)b * 4096;
  const float* gr1 = g1 + (long)b * 4096;
  float gi = gr0[h] + gr1[h] + bih[h] + bhh[h];
  float gf = gr0[1024 + h] + gr1[1024 + h] + bih[1024 + h] + bhh[1024 + h];
  float gg = gr0[2048 + h] + gr1[2048 + h] + bih[2048 + h] + bhh[2048 + h];
  float go = gr0[3072 + h] + gr1[3072 + h] + bih[3072 + h] + bhh[3072 + h];
  float si = 1.f / (1.f + __expf(-gi));
  float sf = 1.f / (1.f + __expf(-gf));
  float so = 1.f / (1.f + __expf(-go));
  float tg = 1.f - 2.f / (__expf(2.f * gg) + 1.f);
  float c2 = sf * cin[idx] + si * tg;
  float tc = 1.f - 2.f / (__expf(2.f * c2) + 1.f);
  float h2 = so * tc;
  cout[idx] = c2;
  hout[idx] = h2;
  hb[idx] = f2bf(h2);
}

extern "C" void kernel_launch(void* const* d_in, const int* in_sizes, int n_in,
                              void* d_out, int out_size, void* d_ws, size_t ws_size,
                              hipStream_t stream) {
  const int* ids = (const int*)d_in[0];
  const float* hidden = (const float*)d_in[1];
  const float* cell = (const float*)d_in[2];
  const float* enc = (const float*)d_in[3];
  const float* emb = (const float*)d_in[4];
  const float* U = (const float*)d_in[5];
  const float* W = (const float*)d_in[6];
  const float* Vw = (const float*)d_in[7];
  const float* Wih0 = (const float*)d_in[8];
  const float* Whh0 = (const float*)d_in[9];
  const float* bih0 = (const float*)d_in[10];
  const float* bhh0 = (const float*)d_in[11];
  const float* Wih1 = (const float*)d_in[12];
  const float* Whh1 = (const float*)d_in[13];
  const float* bih1 = (const float*)d_in[14];
  const float* bhh1 = (const float*)d_in[15];
  const float* out_w = (const float*)d_in[16];
  const float* out_b = (const float*)d_in[17];
  float* out = (float*)d_out;
  char* ws = (char*)d_ws;
  (void)in_sizes; (void)n_in; (void)out_size; (void)ws_size;

  unsigned short* outwb  = (unsigned short*)(ws + OFF_OUTW);
  unsigned short* hid0b  = (unsigned short*)(ws + OFF_HID0);
  unsigned short* hlastb = (unsigned short*)(ws + OFF_HLAST);
  unsigned short* Utb    = (unsigned short*)(ws + OFF_UT);
  unsigned short* Wtb    = (unsigned short*)(ws + OFF_WT);
  float*          t2     = (float*)(ws + OFF_T2);
  float*          e      = (float*)(ws + OFF_E);
  unsigned short* embb   = (unsigned short*)(ws + OFF_EMB);
  unsigned short* ctb    = (unsigned short*)(ws + OFF_CT);
  float*          g      = (float*)(ws + OFF_G);
  float*          gB     = (float*)(ws + OFF_SCRATCH);
  unsigned short* h0b    = (unsigned short*)(ws + OFF_H0B);
  unsigned short* h1b    = (unsigned short*)(ws + OFF_H1B);

  float* out_logits = out;
  float* h_new = out + BB * VV;
  float* c_new = h_new + 2 * BB * HH;

  // ---- prep ----
  cvt_small<<<1152, 256, 0, stream>>>(hidden, out_w, ws);
  transpose_cvt2<<<dim3(32, 32, 2), 256, 0, stream>>>(U, W, ws);
  build_xemb<<<128, 256, 0, stream>>>(ids, emb, embb);
  hipMemsetAsync(e, 0, (size_t)BB * SS * 4, stream);

  // ---- t2 = hidden[1] @ W (B = Wt bf16) ----
  gemm_seg<0><<<dim3(4, 16, 1), 256, 0, stream>>>(hlastb, 1024, nullptr, 0, nullptr,
                                                  Wtb, 1024, nullptr, t2, t2, HH, 1024, 1024);

  // ---- scores e (A = enc f32 on-the-fly, 128x256 tile) ----
  (void)hipFuncSetAttribute(reinterpret_cast<const void*>(gemm_score128),
                            hipFuncAttributeMaxDynamicSharedMemorySize, 98304);
  gemm_score128<<<dim3(4, 256), 512, 98304, stream>>>(enc, Utb, t2, Vw, e);

  // ---- fused softmax + context (enc f32, L3-warm) ----
  softmax_ctx<<<256, 256, 0, stream>>>(e, enc, ctb);

  // ---- LSTM layer 0: g = [emb | ct | hid0] @ [Wih0 | Whh0]^T (weights f32) ----
  gemm_seg<1><<<dim3(4, 64, 2), 256, 0, stream>>>(embb, 256, ctb, 1024, hid0b,
                                                  Wih0, 1280, Whh0, g, gB, 4 * HH, 2304, 1152);
  lstm_cell<<<BB * HH / 256, 256, 0, stream>>>(g, gB, bih0, bhh0, cell, h_new, c_new, h0b);

  // ---- LSTM layer 1: g = [h0 | hid1] @ [Wih1 | Whh1]^T (weights f32) ----
  gemm_seg<1><<<dim3(4, 64, 2), 256, 0, stream>>>(h0b, 1024, hlastb, 1024, nullptr,
                                                  Wih1, 1024, Whh1, g, gB, 4 * HH, 2048, 1024);
  lstm_cell<<<BB * HH / 256, 256, 0, stream>>>(g, gB, bih1, bhh1, cell + BB * HH,
                                               h_new + BB * HH, c_new + BB * HH, h1b);

  // ---- output projection ----
  init_out_bias<<<BB * VV / 256, 256, 0, stream>>>(out_b, out_logits);
  gemm_outproj<<<dim3(4, 8), 256, 0, stream>>>(h1b, outwb, out_logits);
}

// Round 9
// 255.367 us; speedup vs baseline: 1.4515x; 1.0204x over previous
//
#include <hip/hip_runtime.h>
#include <stdint.h>

// dims
#define BB 512
#define SS 64
#define HH 1024
#define EE 256
#define VV 128

typedef __attribute__((ext_vector_type(8))) short bf16x8;
typedef __attribute__((ext_vector_type(4))) float f32x4;
typedef __attribute__((ext_vector_type(8))) unsigned short u16x8;

// ---- workspace layout (bytes, all 256-aligned) ----
constexpr size_t OFF_SCRATCH = 0;                         // 64MB scratch (gate partial-1)
constexpr size_t OFF_OUTW  = OFF_SCRATCH + 67108864UL;    // 128x1024 bf16
constexpr size_t OFF_HID0  = OFF_OUTW  + 262144UL;        // 512x1024 bf16 (input hidden[0])
constexpr size_t OFF_HLAST = OFF_HID0  + 1048576UL;       // 512x1024 bf16 (input hidden[1])
constexpr size_t OFF_UT    = OFF_HLAST + 1048576UL;       // 1024x1024 bf16 (U^T)
constexpr size_t OFF_WT    = OFF_UT    + 2097152UL;       // 1024x1024 bf16 (W^T)
constexpr size_t OFF_T2    = OFF_WT    + 2097152UL;       // 512x1024 f32
constexpr size_t OFF_E     = OFF_T2    + 2097152UL;       // 512x64 f32
constexpr size_t OFF_EMB   = OFF_E     + 131072UL;        // 512x256 bf16
constexpr size_t OFF_CT    = OFF_EMB   + 262144UL;        // 512x1024 bf16
constexpr size_t OFF_G     = OFF_CT    + 1048576UL;       // 512x4096 f32 (gate partial-0)
constexpr size_t OFF_H0B   = OFF_G     + 8388608UL;       // 512x1024 bf16
constexpr size_t OFF_H1B   = OFF_H0B   + 1048576UL;       // 512x1024 bf16

__device__ __forceinline__ unsigned short f2bf(float f) {
  unsigned int u = __float_as_uint(f);
  unsigned int r = (u + 0x7FFFu + ((u >> 16) & 1u)) >> 16;
  return (unsigned short)r;
}
__device__ __forceinline__ float bf2f(unsigned short h) {
  return __uint_as_float(((unsigned int)h) << 16);
}

__device__ __forceinline__ void gload_lds16(const void* g, void* l) {
  __builtin_amdgcn_global_load_lds(
      (const __attribute__((address_space(1))) unsigned int*)g,
      (__attribute__((address_space(3))) unsigned int*)l, 16, 0, 0);
}

// ---------------- small conversions: hid (both layers, contiguous) + out_w ----------------
__global__ __launch_bounds__(256) void cvt_small(const float* __restrict__ hid,
                                                 const float* __restrict__ outw,
                                                 char* __restrict__ ws) {
  int i = blockIdx.x * 256 + threadIdx.x;  // 294912 float4 units
  const float4* src;
  ushort4* dst;
  int j;
  if (i < 262144) { src = (const float4*)hid;  dst = (ushort4*)(ws + OFF_HID0); j = i; }
  else            { src = (const float4*)outw; dst = (ushort4*)(ws + OFF_OUTW); j = i - 262144; }
  float4 v = src[j];
  ushort4 o;
  o.x = f2bf(v.x); o.y = f2bf(v.y); o.z = f2bf(v.z); o.w = f2bf(v.w);
  dst[j] = o;
}

// ---------------- transpose-convert U and W (z selects) ----------------
__global__ void transpose_cvt2(const float* __restrict__ U, const float* __restrict__ W,
                               char* __restrict__ ws) {
  __shared__ float tile[32][33];
  const float* in = blockIdx.z ? W : U;
  unsigned short* out = (unsigned short*)(ws + (blockIdx.z ? OFF_WT : OFF_UT));
  int bc = blockIdx.x * 32, br = blockIdx.y * 32;
  int tx = threadIdx.x & 31, ty = threadIdx.x >> 5;
#pragma unroll
  for (int i = 0; i < 32; i += 8)
    tile[ty + i][tx] = in[(long)(br + ty + i) * HH + bc + tx];
  __syncthreads();
#pragma unroll
  for (int i = 0; i < 32; i += 8)
    out[(long)(bc + ty + i) * HH + br + tx] = f2bf(tile[tx][ty + i]);
}

// ---------------- embedded token gather -> bf16 ----------------
__global__ void build_xemb(const int* __restrict__ ids, const float* __restrict__ emb,
                           unsigned short* __restrict__ embb) {
  int t = blockIdx.x * 256 + threadIdx.x;  // 32768 float4s
  int b = t >> 6, c4 = t & 63;
  float4 v = ((const float4*)(emb + (long)ids[b] * 256))[c4];
  ushort4 o;
  o.x = f2bf(v.x); o.y = f2bf(v.y); o.z = f2bf(v.z); o.w = f2bf(v.w);
  ((ushort4*)embb)[t] = o;
}

// ---------------- segmented bf16 GEMM, split-K; B either bf16 (gload_lds) or f32 (reg-cvt) ----
template <int BF32>
__global__ __launch_bounds__(256) void gemm_seg(
    const unsigned short* __restrict__ A0, int KA0,
    const unsigned short* __restrict__ A1, int KA1,
    const unsigned short* __restrict__ A2,
    const void* __restrict__ B0v, int KB0, const void* __restrict__ B1v,
    float* __restrict__ C0p, float* __restrict__ C1p, int N, int Ktot, int Khalf) {
  __shared__ alignas(128) unsigned short lA[128 * 64];
  __shared__ alignas(128) unsigned short lB[64 * 64];
  const int tid = threadIdx.x;
  const int lane = tid & 63, wid = tid >> 6;
  const int wr = wid >> 1, wc = wid & 1;
  const int fr = lane & 15, fg = lane >> 4;
  f32x4 acc[4][2] = {};
  const long rowA0 = (long)blockIdx.x * 128;
  const long rowB0 = (long)blockIdx.y * 64;
  const int ktb = blockIdx.z * Khalf;
  int kte = ktb + Khalf; if (kte > Ktot) kte = Ktot;
  float* C = blockIdx.z ? C1p : C0p;
  for (int kt = ktb; kt < kte; kt += 64) {
    const unsigned short* Ap; int ka, lda;
    if (kt < KA0)            { Ap = A0; ka = kt;             lda = KA0; }
    else if (kt < KA0 + KA1) { Ap = A1; ka = kt - KA0;       lda = KA1; }
    else                     { Ap = A2; ka = kt - KA0 - KA1; lda = 1024; }
    if constexpr (BF32) {
      const float* Bp; int kb, ldb;
      if (kt < KB0) { Bp = (const float*)B0v; kb = kt;       ldb = KB0; }
      else          { Bp = (const float*)B1v; kb = kt - KB0; ldb = 1024; }
      const int brow = tid >> 2, bkq = tid & 3;
      const f32x4* bs = (const f32x4*)(Bp + (rowB0 + brow) * (long)ldb + kb) + bkq * 4;
      f32x4 q0 = bs[0], q1 = bs[1], q2 = bs[2], q3 = bs[3];
#pragma unroll
      for (int j = 0; j < 4; ++j) {
        int c = j * 256 + tid;
        int r = c >> 3, cc = c & 7;
        int sc = cc ^ ((r >> 1) & 7);
        gload_lds16(Ap + (rowA0 + r) * (long)lda + ka + sc * 8, &lA[c * 8]);
      }
      const int bx = (brow >> 1) & 7;
      u16x8 w0, w1;
#pragma unroll
      for (int j = 0; j < 4; ++j) {
        w0[j] = f2bf(q0[j]); w0[4 + j] = f2bf(q1[j]);
        w1[j] = f2bf(q2[j]); w1[4 + j] = f2bf(q3[j]);
      }
      *(u16x8*)&lB[brow * 64 + (((bkq * 2) ^ bx) * 8)] = w0;
      *(u16x8*)&lB[brow * 64 + (((bkq * 2 + 1) ^ bx) * 8)] = w1;
    } else {
      const unsigned short* Bp; int kb, ldb;
      if (kt < KB0) { Bp = (const unsigned short*)B0v; kb = kt;       ldb = KB0; }
      else          { Bp = (const unsigned short*)B1v; kb = kt - KB0; ldb = 1024; }
#pragma unroll
      for (int j = 0; j < 4; ++j) {
        int c = j * 256 + tid;
        int r = c >> 3, cc = c & 7;
        int sc = cc ^ ((r >> 1) & 7);
        gload_lds16(Ap + (rowA0 + r) * (long)lda + ka + sc * 8, &lA[c * 8]);
      }
#pragma unroll
      for (int j = 0; j < 2; ++j) {
        int c = j * 256 + tid;
        int r = c >> 3, cc = c & 7;
        int sc = cc ^ ((r >> 1) & 7);
        gload_lds16(Bp + (rowB0 + r) * (long)ldb + kb + sc * 8, &lB[c * 8]);
      }
    }
    __syncthreads();
#pragma unroll
    for (int kk = 0; kk < 64; kk += 32) {
      bf16x8 af[4], bfv[2];
#pragma unroll
      for (int m = 0; m < 4; ++m) {
        int row = wr * 64 + m * 16 + fr;
        int ch = ((kk >> 3) + fg) ^ ((row >> 1) & 7);
        af[m] = *(const bf16x8*)&lA[row * 64 + ch * 8];
      }
#pragma unroll
      for (int n = 0; n < 2; ++n) {
        int row = wc * 32 + n * 16 + fr;
        int ch = ((kk >> 3) + fg) ^ ((row >> 1) & 7);
        bfv[n] = *(const bf16x8*)&lB[row * 64 + ch * 8];
      }
#pragma unroll
      for (int m = 0; m < 4; ++m)
#pragma unroll
        for (int n = 0; n < 2; ++n)
          acc[m][n] = __builtin_amdgcn_mfma_f32_16x16x32_bf16(af[m], bfv[n],
                                                              acc[m][n], 0, 0, 0);
    }
    __syncthreads();
  }
#pragma unroll
  for (int m = 0; m < 4; ++m)
#pragma unroll
    for (int n = 0; n < 2; ++n)
#pragma unroll
      for (int r = 0; r < 4; ++r) {
        long grow = rowA0 + wr * 64 + m * 16 + fg * 4 + r;
        long gcol = rowB0 + wc * 32 + n * 16 + fr;
        C[grow * N + gcol] = acc[m][n][r];
      }
}

// ---------------- out projection, split-K, atomic accumulate ----------------
__global__ __launch_bounds__(256) void gemm_outproj(
    const unsigned short* __restrict__ A, const unsigned short* __restrict__ Bt,
    float* __restrict__ C) {
  __shared__ alignas(128) unsigned short lA[128 * 64];
  __shared__ alignas(128) unsigned short lB[128 * 64];
  const int tid = threadIdx.x;
  const int lane = tid & 63, wid = tid >> 6;
  const int wr = wid >> 1, wc = wid & 1;
  const int fr = lane & 15, fg = lane >> 4;
  f32x4 acc[4][4] = {};
  const long rowA0 = (long)blockIdx.x * 128;
  const int k0 = blockIdx.y * 128;
  for (int kt = k0; kt < k0 + 128; kt += 64) {
#pragma unroll
    for (int j = 0; j < 4; ++j) {
      int c = j * 256 + tid;
      int r = c >> 3, cc = c & 7;
      gload_lds16(A + (rowA0 + r) * 1024 + kt + cc * 8, &lA[c * 8]);
    }
#pragma unroll
    for (int j = 0; j < 4; ++j) {
      int c = j * 256 + tid;
      int r = c >> 3, cc = c & 7;
      gload_lds16(Bt + (long)r * 1024 + kt + cc * 8, &lB[c * 8]);
    }
    __syncthreads();
#pragma unroll
    for (int kk = 0; kk < 64; kk += 32) {
      bf16x8 af[4], bfv[4];
#pragma unroll
      for (int m = 0; m < 4; ++m)
        af[m] = *(const bf16x8*)&lA[(wr * 64 + m * 16 + fr) * 64 + kk + fg * 8];
#pragma unroll
      for (int n = 0; n < 4; ++n)
        bfv[n] = *(const bf16x8*)&lB[(wc * 64 + n * 16 + fr) * 64 + kk + fg * 8];
#pragma unroll
      for (int m = 0; m < 4; ++m)
#pragma unroll
        for (int n = 0; n < 4; ++n)
          acc[m][n] = __builtin_amdgcn_mfma_f32_16x16x32_bf16(af[m], bfv[n],
                                                              acc[m][n], 0, 0, 0);
    }
    __syncthreads();
  }
#pragma unroll
  for (int m = 0; m < 4; ++m)
#pragma unroll
    for (int n = 0; n < 4; ++n)
#pragma unroll
      for (int r = 0; r < 4; ++r) {
        long grow = rowA0 + wr * 64 + m * 16 + fg * 4 + r;
        long gcol = wc * 64 + n * 16 + fr;
        atomicAdd(&C[grow * 128 + gcol], acc[m][n][r]);
      }
}

__global__ void init_out_bias(const float* __restrict__ ob, float* __restrict__ out) {
  int i = blockIdx.x * 256 + threadIdx.x;
  out[i] = ob[i & 127];
}

// ---------------- 256x256 fused score GEMM, A = enc f32 on-the-fly, 1 barrier/K-tile ------
// __launch_bounds__(512,1): LDS (128KB) caps at 1 block/CU -> 2 waves/SIMD -> 256 VGPR/wave
// available; acc 128 + areg 32 + frags fits with NO spill (r7's (512,2) forced 128 -> spilled).
// LDS per buf (32768 shorts): A.kh0 @0, A.kh1 @8192, B.kh0 @16384, B.kh1 @24576;
// each region [256 rows][32 k] bf16, slot swizzle phys = logical ^ ((row>>1)&3) ^ kh.
// vmcnt invariant: entering iter u, A(u+1)'s 8 loads outstanding (oldest).
__global__ __launch_bounds__(512, 1) void gemm_score256(
    const float* __restrict__ Af, const unsigned short* __restrict__ Bt,
    const float* __restrict__ t2, const float* __restrict__ Vw,
    float* __restrict__ e) {
  extern __shared__ unsigned short smem[];  // 2 x 32768 shorts = 128 KiB
  const int tid = threadIdx.x;
  const int lane = tid & 63, wid = tid >> 6;
  const int wr = wid >> 2;       // M half (128 rows)
  const int wcc = wid & 3;       // N quarter (64 cols)
  const int fr = lane & 15, fg = lane >> 4;
  int flat = blockIdx.y * 4 + blockIdx.x;
  int swz = (flat & 7) * 64 + (flat >> 3);     // XCD-chunked swizzle (512 = 8x64)
  const long rowA0 = (long)(swz >> 2) * 256;
  const long rowB0 = (long)(swz & 3) * 256;

  f32x4 acc[8][4] = {};

  // A staging: thread -> (arow = tid>>1, akh = tid&1), 32 floats of one row-khalf
  const int arow = tid >> 1, akh = tid & 1;
  const float* ag = Af + (rowA0 + arow) * 1024 + akh * 32;
  const int awx = (arow >> 1) & 3;
  f32x4 areg[8];

  auto issueA = [&](int kt) {
    const f32x4* p = (const f32x4*)(ag + kt * 64);
#pragma unroll
    for (int j = 0; j < 8; ++j) areg[j] = p[j];
  };
  auto writeA = [&](int buf) {
    unsigned short* wb = smem + buf * 32768 + akh * 8192 + arow * 32;
#pragma unroll
    for (int s = 0; s < 4; ++s) {
      u16x8 o;
#pragma unroll
      for (int q = 0; q < 8; ++q) o[q] = f2bf(areg[s * 2 + (q >> 2)][q & 3]);
      *(u16x8*)(wb + (((s ^ awx ^ akh) & 3) * 8)) = o;
    }
  };
  auto stageB = [&](int buf, int kt) {
#pragma unroll
    for (int kh = 0; kh < 2; ++kh) {
      unsigned short* dst = smem + buf * 32768 + (2 + kh) * 8192;
      int kb = kt * 64 + kh * 32;
#pragma unroll
      for (int j = 0; j < 2; ++j) {
        int c = j * 512 + tid;
        int row = c >> 2;
        int fgl = (c & 3) ^ ((row >> 1) & 3);
        gload_lds16(Bt + (rowB0 + row) * 1024L + kb + fgl * 8, dst + c * 8);
      }
    }
  };
  auto readA4 = [&](int buf, int kh, int mh, bf16x8* af) {
    const unsigned short* rg = smem + buf * 32768 + kh * 8192;
#pragma unroll
    for (int m = 0; m < 4; ++m) {
      int row = wr * 128 + mh * 64 + m * 16 + fr;
      int slot = (fg ^ ((row >> 1) & 3) ^ kh) & 3;
      af[m] = *(const bf16x8*)(rg + row * 32 + slot * 8);
    }
  };
  auto readB4 = [&](int buf, int kh, bf16x8* bv) {
    const unsigned short* rg = smem + buf * 32768 + (2 + kh) * 8192;
#pragma unroll
    for (int n = 0; n < 4; ++n) {
      int row = wcc * 64 + n * 16 + fr;
      int slot = fg ^ ((row >> 1) & 3);
      bv[n] = *(const bf16x8*)(rg + row * 32 + slot * 8);
    }
  };
  auto mfma16 = [&](int mh, const bf16x8* af, const bf16x8* bv) {
    __builtin_amdgcn_s_setprio(1);
#pragma unroll
    for (int m = 0; m < 4; ++m)
#pragma unroll
      for (int n = 0; n < 4; ++n)
        acc[mh * 4 + m][n] = __builtin_amdgcn_mfma_f32_16x16x32_bf16(
            af[m], bv[n], acc[mh * 4 + m][n], 0, 0, 0);
    __builtin_amdgcn_s_setprio(0);
  };

  // ---- prologue: tile0 -> buf0; A(1) in flight ----
  issueA(0);
  stageB(0, 0);
  asm volatile("s_waitcnt vmcnt(4)" ::: "memory");   // A(0) regs done (B(0) 4 newer out)
  writeA(0);
  issueA(1);
  asm volatile("s_waitcnt lgkmcnt(0)" ::: "memory"); // A-writes drained
  asm volatile("s_waitcnt vmcnt(8)" ::: "memory");   // B(0) done; A(1) 8 outstanding
  __builtin_amdgcn_s_barrier();
  __builtin_amdgcn_sched_barrier(0);

  for (int u = 0; u < 16; ++u) {
    const int cur = u & 1, nxt = cur ^ 1;
    stageB(nxt, (u + 1) & 15);                       // +4 gloads (12 out)
    bf16x8 af[4], bv[4];
    readB4(cur, 0, bv);
    readA4(cur, 0, 0, af);
    mfma16(0, af, bv);
    readA4(cur, 0, 1, af);
    mfma16(1, af, bv);
    writeA(nxt);                                     // data-dep: compiler waits vmcnt(4)
    issueA((u + 2) & 15);                            // +8 (B(u+1) 4 oldest, A(u+2) 8)
    readB4(cur, 1, bv);
    readA4(cur, 1, 0, af);
    mfma16(0, af, bv);
    readA4(cur, 1, 1, af);
    asm volatile("s_waitcnt lgkmcnt(0)" ::: "memory");
    mfma16(1, af, bv);
    asm volatile("s_waitcnt vmcnt(8)" ::: "memory"); // B(u+1) done; A(u+2) stays out
    __builtin_amdgcn_s_barrier();
    __builtin_amdgcn_sched_barrier(0);
  }
  asm volatile("s_waitcnt vmcnt(0)" ::: "memory");

  // ---- epilogue: e[row] += sum_cols tanh(acc + t2) * Vw ----
  float t2v[2][4], vw[4];
#pragma unroll
  for (int n = 0; n < 4; ++n) {
    long col = rowB0 + wcc * 64 + n * 16 + fr;
    vw[n] = Vw[col];
#pragma unroll
    for (int h = 0; h < 2; ++h) {
      long b = (rowA0 >> 6) + wr * 2 + h;
      t2v[h][n] = t2[b * HH + col];
    }
  }
#pragma unroll
  for (int i = 0; i < 8; ++i) {
    int hsel = i >> 2;
    float part[4] = {0.f, 0.f, 0.f, 0.f};
#pragma unroll
    for (int n = 0; n < 4; ++n) {
#pragma unroll
      for (int r = 0; r < 4; ++r) {
        float tval = acc[i][n][r] + t2v[hsel][n];
        float th = 1.f - 2.f / (__expf(2.f * tval) + 1.f);
        part[r] += th * vw[n];
      }
    }
#pragma unroll
    for (int r = 0; r < 4; ++r) {
      float p = part[r];
      p += __shfl_xor(p, 1);
      p += __shfl_xor(p, 2);
      p += __shfl_xor(p, 4);
      p += __shfl_xor(p, 8);
      if (fr == 0)
        atomicAdd(&e[rowA0 + wr * 128 + i * 16 + fg * 4 + r], p);
    }
  }
}

// ---------------- fused softmax (S=64) + context (reads enc f32, L3-warm) -> bf16 ----------
__global__ void softmax_ctx(const float* __restrict__ e,
                            const float* __restrict__ enc,
                            unsigned short* __restrict__ ctb) {
  __shared__ float als[2][64];
  const int tid = threadIdx.x;
  const int bpair = blockIdx.x;
  if (tid < 128) {
    int b = bpair * 2 + (tid >> 6), s = tid & 63;
    float v = e[b * 64 + s];
    float mx = v;
#pragma unroll
    for (int o = 32; o; o >>= 1) mx = fmaxf(mx, __shfl_xor(mx, o));
    float ex = __expf(v - mx);
    float sm = ex;
#pragma unroll
    for (int o = 32; o; o >>= 1) sm += __shfl_xor(sm, o);
    als[tid >> 6][s] = ex / sm;
  }
  __syncthreads();
  int bi = tid >> 7, hg = tid & 127;
  int b = bpair * 2 + bi;
  const float* er = enc + (long)b * (SS * HH) + hg * 8;
  float s[8] = {0.f, 0.f, 0.f, 0.f, 0.f, 0.f, 0.f, 0.f};
  for (int i = 0; i < 64; ++i) {
    float av = als[bi][i];
    f32x4 v0 = *(const f32x4*)(er + (long)i * HH);
    f32x4 v1 = *(const f32x4*)(er + (long)i * HH + 4);
#pragma unroll
    for (int j = 0; j < 4; ++j) { s[j] += av * v0[j]; s[4 + j] += av * v1[j]; }
  }
  unsigned short* dst = ctb + (long)b * HH + hg * 8;
#pragma unroll
  for (int j = 0; j < 8; ++j) dst[j] = f2bf(s[j]);
}

// ---------------- LSTM cell elementwise (sums two split-K partials) ----------------
__global__ void lstm_cell(const float* __restrict__ g0, const float* __restrict__ g1,
                          const float* __restrict__ bih, const float* __restrict__ bhh,
                          const float* __restrict__ cin,
                          float* __restrict__ hout, float* __restrict__ cout,
                          unsigned short* __restrict__ hb) {
  int idx = blockIdx.x * 256 + threadIdx.x;  // 512*1024
  int b = idx >> 10, h = idx & 1023;
  const float* gr0 = g0 + (long)b * 4096;
  const float* gr1 = g1 + (long)b * 4096;
  float gi = gr0[h] + gr1[h] + bih[h] + bhh[h];
  float gf = gr0[1024 + h] + gr1[1024 + h] + bih[1024 + h] + bhh[1024 + h];
  float gg = gr0[2048 + h] + gr1[2048 + h] + bih[2048 + h] + bhh[2048 + h];
  float go = gr0[3072 + h] + gr1[3072 + h] + bih[3072 + h] + bhh[3072 + h];
  float si = 1.f / (1.f + __expf(-gi));
  float sf = 1.f / (1.f + __expf(-gf));
  float so = 1.f / (1.f + __expf(-go));
  float tg = 1.f - 2.f / (__expf(2.f * gg) + 1.f);
  float c2 = sf * cin[idx] + si * tg;
  float tc = 1.f - 2.f / (__expf(2.f * c2) + 1.f);
  float h2 = so * tc;
  cout[idx] = c2;
  hout[idx] = h2;
  hb[idx] = f2bf(h2);
}

extern "C" void kernel_launch(void* const* d_in, const int* in_sizes, int n_in,
                              void* d_out, int out_size, void* d_ws, size_t ws_size,
                              hipStream_t stream) {
  const int* ids = (const int*)d_in[0];
  const float* hidden = (const float*)d_in[1];
  const float* cell = (const float*)d_in[2];
  const float* enc = (const float*)d_in[3];
  const float* emb = (const float*)d_in[4];
  const float* U = (const float*)d_in[5];
  const float* W = (const float*)d_in[6];
  const float* Vw = (const float*)d_in[7];
  const float* Wih0 = (const float*)d_in[8];
  const float* Whh0 = (const float*)d_in[9];
  const float* bih0 = (const float*)d_in[10];
  const float* bhh0 = (const float*)d_in[11];
  const float* Wih1 = (const float*)d_in[12];
  const float* Whh1 = (const float*)d_in[13];
  const float* bih1 = (const float*)d_in[14];
  const float* bhh1 = (const float*)d_in[15];
  const float* out_w = (const float*)d_in[16];
  const float* out_b = (const float*)d_in[17];
  float* out = (float*)d_out;
  char* ws = (char*)d_ws;
  (void)in_sizes; (void)n_in; (void)out_size; (void)ws_size;

  unsigned short* outwb  = (unsigned short*)(ws + OFF_OUTW);
  unsigned short* hid0b  = (unsigned short*)(ws + OFF_HID0);
  unsigned short* hlastb = (unsigned short*)(ws + OFF_HLAST);
  unsigned short* Utb    = (unsigned short*)(ws + OFF_UT);
  unsigned short* Wtb    = (unsigned short*)(ws + OFF_WT);
  float*          t2     = (float*)(ws + OFF_T2);
  float*          e      = (float*)(ws + OFF_E);
  unsigned short* embb   = (unsigned short*)(ws + OFF_EMB);
  unsigned short* ctb    = (unsigned short*)(ws + OFF_CT);
  float*          g      = (float*)(ws + OFF_G);
  float*          gB     = (float*)(ws + OFF_SCRATCH);
  unsigned short* h0b    = (unsigned short*)(ws + OFF_H0B);
  unsigned short* h1b    = (unsigned short*)(ws + OFF_H1B);

  float* out_logits = out;
  float* h_new = out + BB * VV;
  float* c_new = h_new + 2 * BB * HH;

  // ---- prep ----
  cvt_small<<<1152, 256, 0, stream>>>(hidden, out_w, ws);
  transpose_cvt2<<<dim3(32, 32, 2), 256, 0, stream>>>(U, W, ws);
  build_xemb<<<128, 256, 0, stream>>>(ids, emb, embb);
  hipMemsetAsync(e, 0, (size_t)BB * SS * 4, stream);

  // ---- t2 = hidden[1] @ W (B = Wt bf16) ----
  gemm_seg<0><<<dim3(4, 16, 1), 256, 0, stream>>>(hlastb, 1024, nullptr, 0, nullptr,
                                                  Wtb, 1024, nullptr, t2, t2, HH, 1024, 1024);

  // ---- scores e (A = enc f32 on-the-fly, 256x256 tile) ----
  (void)hipFuncSetAttribute(reinterpret_cast<const void*>(gemm_score256),
                            hipFuncAttributeMaxDynamicSharedMemorySize, 131072);
  gemm_score256<<<dim3(4, 128), 512, 131072, stream>>>(enc, Utb, t2, Vw, e);

  // ---- fused softmax + context (enc f32, L3-warm) ----
  softmax_ctx<<<256, 256, 0, stream>>>(e, enc, ctb);

  // ---- LSTM layer 0: g = [emb | ct | hid0] @ [Wih0 | Whh0]^T (weights f32) ----
  gemm_seg<1><<<dim3(4, 64, 2), 256, 0, stream>>>(embb, 256, ctb, 1024, hid0b,
                                                  Wih0, 1280, Whh0, g, gB, 4 * HH, 2304, 1152);
  lstm_cell<<<BB * HH / 256, 256, 0, stream>>>(g, gB, bih0, bhh0, cell, h_new, c_new, h0b);

  // ---- LSTM layer 1: g = [h0 | hid1] @ [Wih1 | Whh1]^T (weights f32) ----
  gemm_seg<1><<<dim3(4, 64, 2), 256, 0, stream>>>(h0b, 1024, hlastb, 1024, nullptr,
                                                  Wih1, 1024, Whh1, g, gB, 4 * HH, 2048, 1024);
  lstm_cell<<<BB * HH / 256, 256, 0, stream>>>(g, gB, bih1, bhh1, cell + BB * HH,
                                               h_new + BB * HH, c_new + BB * HH, h1b);

  // ---- output projection ----
  init_out_bias<<<BB * VV / 256, 256, 0, stream>>>(out_b, out_logits);
  gemm_outproj<<<dim3(4, 8), 256, 0, stream>>>(h1b, outwb, out_logits);
}